// Round 4
// baseline (155.787 us; speedup 1.0000x reference)
//
#include <hip/hip_runtime.h>
#include <math.h>

#define N 1024
#define IN_DIM 16
#define HID 64
#define MAXD 64

__device__ __forceinline__ float sigmoidf_(float x) {
    return 1.0f / (1.0f + __expf(-x));
}

// ---------------- fused init: encoder(+proj0) blocks [0,256), CSR blocks [256,1280)
__global__ void init_kernel(const float* __restrict__ X,
                            const float* __restrict__ W_enc,
                            const float* __restrict__ b_enc,
                            const float* __restrict__ W_msg,
                            const float* __restrict__ b_msg,
                            const float* __restrict__ A,
                            const float* __restrict__ E,
                            float* __restrict__ h,
                            float* __restrict__ proj,
                            int* __restrict__ nbr,
                            float* __restrict__ ev,
                            float* __restrict__ deg) {
    int bid = blockIdx.x;
    int tid = threadIdx.x;
    int wave = tid >> 6;
    int lane = tid & 63;

    if (bid < 256) {
        // ---- encoder + proj0: node u = bid*4 + wave, lane = hidden index ----
        int u = bid * 4 + wave;
        __shared__ float sh[4][HID];
        float acc = b_enc[lane];
#pragma unroll
        for (int k = 0; k < IN_DIM; ++k)
            acc += X[u * IN_DIM + k] * W_enc[lane * IN_DIM + k];
        float hv = tanhf(acc);
        h[u * HID + lane] = hv;
        sh[wave][lane] = hv;
        __syncthreads();
        float pacc = b_msg[lane];
        const float4* h4 = (const float4*)sh[wave];
#pragma unroll
        for (int k4 = 0; k4 < HID / 4; ++k4) {
            float4 hh = h4[k4];
            const float* w = &W_msg[lane * (HID + 1) + k4 * 4];
            pacc += hh.x * w[0] + hh.y * w[1] + hh.z * w[2] + hh.w * w[3];
        }
        proj[u * HID + lane] = pacc;
    } else {
        // ---- CSR build: one 256-thread block per row u ----
        int u = bid - 256;
        __shared__ unsigned long long balls[16];
        __shared__ int base[16];
        float evr[4];
        bool has[4];
#pragma unroll
        for (int ci = 0; ci < 4; ++ci) {
            int chunk = wave * 4 + ci;
            int v = chunk * 64 + lane;
            float a = A[u * N + v];
            bool hs = (a > 0.0f);
            has[ci] = hs;
            evr[ci] = E[u * N + v];
            unsigned long long b = __ballot(hs);
            if (lane == 0) balls[chunk] = b;
        }
        __syncthreads();
        if (tid == 0) {
            int s = 0;
#pragma unroll
            for (int c = 0; c < 16; ++c) {
                base[c] = s;
                s += __popcll(balls[c]);
            }
            deg[u] = (float)s;
        }
        __syncthreads();
#pragma unroll
        for (int ci = 0; ci < 4; ++ci) {
            int chunk = wave * 4 + ci;
            if (has[ci]) {
                unsigned long long b = balls[chunk];
                int slot = base[chunk] + __popcll(b & ((1ull << lane) - 1ull));
                if (slot < MAXD) {
                    nbr[u * MAXD + slot] = chunk * 64 + lane;
                    ev[u * MAXD + slot] = evr[ci];
                }
            }
        }
    }
}

// ---------------- fused step: msg-gather + GRU + h_new + proj(h_new) ------------
__global__ void step_kernel(const float* __restrict__ proj,      // proj of h_in
                            const float* __restrict__ W_msg,     // w_e = col HID
                            const float* __restrict__ b_msg,
                            const float* __restrict__ hin,
                            const int* __restrict__ nbr,
                            const float* __restrict__ ev,
                            const float* __restrict__ deg,
                            const float* __restrict__ W_ih,
                            const float* __restrict__ W_hh,
                            const float* __restrict__ b_ih,
                            const float* __restrict__ b_hh,
                            float* __restrict__ hout,
                            float* __restrict__ projout,
                            int do_proj) {
    int wave = threadIdx.x >> 6;     // 4 waves / block, wave = node slot
    int lane = threadIdx.x & 63;     // lane = hidden index
    int u = blockIdx.x * 4 + wave;

    __shared__ float sm[4][2][HID];  // [0]=msgs (later h_new), [1]=h_u

    float we = W_msg[lane * (HID + 1) + HID];
    float d = deg[u];
    int dn = (int)d;
    float s = 0.0f;
    int i = 0;
    for (; i + 4 <= dn; i += 4) {
        int4 nb = *(const int4*)&nbr[u * MAXD + i];
        float4 e4 = *(const float4*)&ev[u * MAXD + i];
        float p0 = proj[nb.x * HID + lane];
        float p1 = proj[nb.y * HID + lane];
        float p2 = proj[nb.z * HID + lane];
        float p3 = proj[nb.w * HID + lane];
        s += tanhf(p0 + e4.x * we);
        s += tanhf(p1 + e4.y * we);
        s += tanhf(p2 + e4.z * we);
        s += tanhf(p3 + e4.w * we);
    }
    for (; i < dn; ++i) {
        int v = nbr[u * MAXD + i];
        float e = ev[u * MAXD + i];
        s += tanhf(proj[v * HID + lane] + e * we);
    }
    float msg = (dn > 0) ? (s / d) : 0.0f;
    float hu = hin[u * HID + lane];

    sm[wave][0][lane] = msg;
    sm[wave][1][lane] = hu;
    __syncthreads();

    // lane j computes gate rows j (r), 64+j (z), 128+j (n)
    float gi[3], gh[3];
    const float4* m4 = (const float4*)sm[wave][0];
    const float4* h4 = (const float4*)sm[wave][1];
#pragma unroll
    for (int g = 0; g < 3; ++g) {
        int row = g * HID + lane;
        float accI = b_ih[row];
        float accH = b_hh[row];
        const float* wi = &W_ih[row * HID];
        const float* wh = &W_hh[row * HID];
#pragma unroll
        for (int k4 = 0; k4 < HID / 4; ++k4) {
            float4 mv = m4[k4];
            float4 hv = h4[k4];
            const float4 wiv = *(const float4*)&wi[k4 * 4];
            const float4 whv = *(const float4*)&wh[k4 * 4];
            accI += mv.x * wiv.x + mv.y * wiv.y + mv.z * wiv.z + mv.w * wiv.w;
            accH += hv.x * whv.x + hv.y * whv.y + hv.z * whv.z + hv.w * whv.w;
        }
        gi[g] = accI;
        gh[g] = accH;
    }
    float r = sigmoidf_(gi[0] + gh[0]);
    float z = sigmoidf_(gi[1] + gh[1]);
    float n = tanhf(gi[2] + r * gh[2]);
    float hnew = (1.0f - z) * n + z * hu;
    hout[u * HID + lane] = hnew;

    if (do_proj) {
        __syncthreads();             // protect sm[wave][0] reuse
        sm[wave][0][lane] = hnew;
        __syncthreads();
        float pacc = b_msg[lane];
        const float4* n4 = (const float4*)sm[wave][0];
#pragma unroll
        for (int k4 = 0; k4 < HID / 4; ++k4) {
            float4 hh = n4[k4];
            const float* w = &W_msg[lane * (HID + 1) + k4 * 4];
            pacc += hh.x * w[0] + hh.y * w[1] + hh.z * w[2] + hh.w * w[3];
        }
        projout[u * HID + lane] = pacc;
    }
}

// ---------------- readout: scalar sigmoid(MLP(cat(h[s], h[t]))) ------------------
__global__ void readout_kernel(const float* __restrict__ h,
                               const float* __restrict__ W_r1,
                               const float* __restrict__ b_r1,
                               const float* __restrict__ W_r2,
                               const float* __restrict__ b_r2,
                               const int* __restrict__ src,
                               const int* __restrict__ tgt,
                               float* __restrict__ out) {
    int lane = threadIdx.x;  // 64 threads, 1 wave; lane = hidden row of W_r1
    int sI = src[0];
    int tI = tgt[0];
    float acc = b_r1[lane];
#pragma unroll 8
    for (int k = 0; k < HID; ++k)
        acc += h[sI * HID + k] * W_r1[lane * (2 * HID) + k];
#pragma unroll 8
    for (int k = 0; k < HID; ++k)
        acc += h[tI * HID + k] * W_r1[lane * (2 * HID) + HID + k];
    float hid = fmaxf(acc, 0.0f);
    float p = hid * W_r2[lane];
#pragma unroll
    for (int off = 32; off > 0; off >>= 1)
        p += __shfl_down(p, off);
    if (lane == 0) out[0] = sigmoidf_(p + b_r2[0]);
}

extern "C" void kernel_launch(void* const* d_in, const int* in_sizes, int n_in,
                              void* d_out, int out_size, void* d_ws, size_t ws_size,
                              hipStream_t stream) {
    const float* A     = (const float*)d_in[0];
    const float* E     = (const float*)d_in[1];
    const float* X     = (const float*)d_in[2];
    const float* W_enc = (const float*)d_in[3];
    const float* b_enc = (const float*)d_in[4];
    const float* W_msg = (const float*)d_in[5];
    const float* b_msg = (const float*)d_in[6];
    const float* W_ih  = (const float*)d_in[7];
    const float* W_hh  = (const float*)d_in[8];
    const float* b_ih  = (const float*)d_in[9];
    const float* b_hh  = (const float*)d_in[10];
    const float* W_r1  = (const float*)d_in[11];
    const float* b_r1  = (const float*)d_in[12];
    const float* W_r2  = (const float*)d_in[13];
    const float* b_r2  = (const float*)d_in[14];
    const int*   src   = (const int*)d_in[15];
    const int*   tgt   = (const int*)d_in[16];
    // steps fixed at 3 in the reference.

    // workspace layout (floats)
    float* ws   = (float*)d_ws;
    float* h0   = ws;                    // N*HID
    float* h1   = h0 + N * HID;          // N*HID
    float* p0   = h1 + N * HID;          // N*HID
    float* p1   = p0 + N * HID;          // N*HID
    float* deg  = p1 + N * HID;          // N
    float* ev   = deg + N;               // N*MAXD
    int*   nbr  = (int*)(ev + N * MAXD); // N*MAXD ints

    init_kernel<<<256 + N, 256, 0, stream>>>(X, W_enc, b_enc, W_msg, b_msg,
                                             A, E, h0, p0, nbr, ev, deg);

    float* hc = h0; float* hn = h1;
    float* pc = p0; float* pn = p1;
    for (int s = 0; s < 3; ++s) {
        step_kernel<<<N / 4, 256, 0, stream>>>(pc, W_msg, b_msg, hc, nbr, ev, deg,
                                               W_ih, W_hh, b_ih, b_hh, hn, pn,
                                               (s < 2) ? 1 : 0);
        float* t = hc; hc = hn; hn = t;
        t = pc; pc = pn; pn = t;
    }

    readout_kernel<<<1, 64, 0, stream>>>(hc, W_r1, b_r1, W_r2, b_r2, src, tgt,
                                         (float*)d_out);
}

// Round 5
// 49.528 us; speedup vs baseline: 3.1454x; 3.1454x over previous
//
#include <hip/hip_runtime.h>
#include <math.h>

#define N 1024
#define IN_DIM 16
#define HID 64
#define MAXD 64

__device__ __forceinline__ float sigmoidf_(float x) {
    return 1.0f / (1.0f + __expf(-x));
}
// fast tanh via exp; exact at +-inf saturation, ~1e-6 rel error
__device__ __forceinline__ float ftanh_(float x) {
    float e = __expf(2.0f * x);
    return 1.0f - 2.0f / (e + 1.0f);
}

// ---- fused init:
//   blocks [0,256)        : encoder + proj0 (4 nodes/block, 1 wave/node)
//   blocks [256,1280)     : CSR build (1 block/row)
//   blocks [1280,1424)    : weight transposes -> ws (coalesced read, scattered write)
__global__ void init_kernel(const float* __restrict__ X,
                            const float* __restrict__ W_enc,
                            const float* __restrict__ b_enc,
                            const float* __restrict__ W_msg,
                            const float* __restrict__ b_msg,
                            const float* __restrict__ W_ih,
                            const float* __restrict__ W_hh,
                            const float* __restrict__ W_r1,
                            const float* __restrict__ A,
                            const float* __restrict__ E,
                            float* __restrict__ h,
                            float* __restrict__ proj,
                            int* __restrict__ nbr,
                            float* __restrict__ ev,
                            float* __restrict__ deg,
                            float* __restrict__ WihT,
                            float* __restrict__ WhhT,
                            float* __restrict__ WmsgT,
                            float* __restrict__ Wr1T) {
    int bid = blockIdx.x;
    int tid = threadIdx.x;
    int wave = tid >> 6;
    int lane = tid & 63;

    if (bid < 256) {
        // ---- encoder + proj0 ----
        int u = bid * 4 + wave;
        __shared__ float sh[4][HID];
        float acc = b_enc[lane];
#pragma unroll
        for (int k = 0; k < IN_DIM; ++k)
            acc += X[u * IN_DIM + k] * W_enc[lane * IN_DIM + k];
        float hv = tanhf(acc);
        h[u * HID + lane] = hv;
        sh[wave][lane] = hv;
        __syncthreads();
        float pacc = b_msg[lane];
        const float4* h4 = (const float4*)sh[wave];
#pragma unroll
        for (int k4 = 0; k4 < HID / 4; ++k4) {
            float4 hh = h4[k4];
            const float* w = &W_msg[lane * (HID + 1) + k4 * 4];
            pacc += hh.x * w[0] + hh.y * w[1] + hh.z * w[2] + hh.w * w[3];
        }
        proj[u * HID + lane] = pacc;
    } else if (bid < 1280) {
        // ---- CSR build: one 256-thread block per row u ----
        int u = bid - 256;
        __shared__ unsigned long long balls[16];
        __shared__ int base[16];
        float evr[4];
        bool has[4];
#pragma unroll
        for (int ci = 0; ci < 4; ++ci) {
            int chunk = wave * 4 + ci;
            int v = chunk * 64 + lane;
            float a = A[u * N + v];
            bool hs = (a > 0.0f);
            has[ci] = hs;
            evr[ci] = E[u * N + v];
            unsigned long long b = __ballot(hs);
            if (lane == 0) balls[chunk] = b;
        }
        __syncthreads();
        if (tid == 0) {
            int s = 0;
#pragma unroll
            for (int c = 0; c < 16; ++c) {
                base[c] = s;
                s += __popcll(balls[c]);
            }
            deg[u] = (float)s;
        }
        __syncthreads();
#pragma unroll
        for (int ci = 0; ci < 4; ++ci) {
            int chunk = wave * 4 + ci;
            if (has[ci]) {
                unsigned long long b = balls[chunk];
                int slot = base[chunk] + __popcll(b & ((1ull << lane) - 1ull));
                if (slot < MAXD) {
                    nbr[u * MAXD + slot] = chunk * 64 + lane;
                    ev[u * MAXD + slot] = evr[ci];
                }
            }
        }
    } else {
        // ---- weight transposes: flat element id over 36864 ----
        int t = (bid - 1280) * 256 + tid;
        if (t < 12288) {                       // W_ihT[k*192+r] = W_ih[r*64+k]
            int r = t >> 6, k = t & 63;
            WihT[k * 192 + r] = W_ih[t];
        } else if (t < 24576) {                // W_hhT
            int t0 = t - 12288;
            int r = t0 >> 6, k = t0 & 63;
            WhhT[k * 192 + r] = W_hh[t0];
        } else if (t < 28672) {                // W_msgT[k*64+j] = W_msg[j*65+k]
            int t0 = t - 24576;
            int j = t0 >> 6, k = t0 & 63;
            WmsgT[k * 64 + j] = W_msg[j * (HID + 1) + k];
        } else {                               // W_r1T[k*64+j] = W_r1[j*128+k]
            int t0 = t - 28672;
            int j = t0 >> 7, k = t0 & 127;
            Wr1T[k * 64 + j] = W_r1[t0];
        }
    }
}

// ---- fused step: msg-gather + GRU + h_new + proj(h_new), coalesced weights ----
__global__ void step_kernel(const float* __restrict__ proj,      // proj of h_in
                            const float* __restrict__ W_msg,     // only w_e col
                            const float* __restrict__ b_msg,
                            const float* __restrict__ hin,
                            const int* __restrict__ nbr,
                            const float* __restrict__ ev,
                            const float* __restrict__ deg,
                            const float* __restrict__ WihT,      // [64][192]
                            const float* __restrict__ WhhT,      // [64][192]
                            const float* __restrict__ WmsgT,     // [64][64]
                            const float* __restrict__ b_ih,
                            const float* __restrict__ b_hh,
                            float* __restrict__ hout,
                            float* __restrict__ projout,
                            int do_proj) {
    int wave = threadIdx.x >> 6;     // 4 waves / block, wave = node slot
    int lane = threadIdx.x & 63;     // lane = hidden index
    int u = blockIdx.x * 4 + wave;

    __shared__ float sm[4][2][HID];  // [0]=msgs (later h_new), [1]=h_u

    float we = W_msg[lane * (HID + 1) + HID];
    float d = deg[u];
    int dn = (int)d;
    float s = 0.0f;
    int i = 0;
    for (; i + 4 <= dn; i += 4) {
        int4 nb = *(const int4*)&nbr[u * MAXD + i];
        float4 e4 = *(const float4*)&ev[u * MAXD + i];
        float p0 = proj[nb.x * HID + lane];
        float p1 = proj[nb.y * HID + lane];
        float p2 = proj[nb.z * HID + lane];
        float p3 = proj[nb.w * HID + lane];
        s += ftanh_(p0 + e4.x * we);
        s += ftanh_(p1 + e4.y * we);
        s += ftanh_(p2 + e4.z * we);
        s += ftanh_(p3 + e4.w * we);
    }
    for (; i < dn; ++i) {
        int v = nbr[u * MAXD + i];
        float e = ev[u * MAXD + i];
        s += ftanh_(proj[v * HID + lane] + e * we);
    }
    float msg = (dn > 0) ? (s / d) : 0.0f;
    float hu = hin[u * HID + lane];

    sm[wave][0][lane] = msg;
    sm[wave][1][lane] = hu;
    __syncthreads();

    // GRU: lane j = output index j; all weight reads coalesced via transposed mats
    float accR  = b_ih[lane]       + b_hh[lane];
    float accZ  = b_ih[64 + lane]  + b_hh[64 + lane];
    float accNi = b_ih[128 + lane];
    float accNh = b_hh[128 + lane];
    const float4* m4 = (const float4*)sm[wave][0];
    const float4* h4 = (const float4*)sm[wave][1];
#pragma unroll
    for (int k4 = 0; k4 < 16; ++k4) {
        float4 mv = m4[k4];
        float4 hv = h4[k4];
#pragma unroll
        for (int t = 0; t < 4; ++t) {
            int k = k4 * 4 + t;
            const float* wi = &WihT[k * 192];
            const float* wh = &WhhT[k * 192];
            float mk = (&mv.x)[t];
            float hk = (&hv.x)[t];
            accR  += mk * wi[lane]       + hk * wh[lane];
            accZ  += mk * wi[64 + lane]  + hk * wh[64 + lane];
            accNi += mk * wi[128 + lane];
            accNh += hk * wh[128 + lane];
        }
    }
    float r = sigmoidf_(accR);
    float z = sigmoidf_(accZ);
    float n = ftanh_(accNi + r * accNh);
    float hnew = (1.0f - z) * n + z * hu;
    hout[u * HID + lane] = hnew;

    if (do_proj) {
        __syncthreads();             // protect sm[wave][0] reuse
        sm[wave][0][lane] = hnew;
        __syncthreads();
        float pacc = b_msg[lane];
        const float4* n4 = (const float4*)sm[wave][0];
#pragma unroll
        for (int k4 = 0; k4 < 16; ++k4) {
            float4 hh = n4[k4];
#pragma unroll
            for (int t = 0; t < 4; ++t) {
                int k = k4 * 4 + t;
                pacc += (&hh.x)[t] * WmsgT[k * 64 + lane];
            }
        }
        projout[u * HID + lane] = pacc;
    }
}

// ---- readout: scalar sigmoid(MLP(cat(h[s], h[t]))), coalesced W_r1T ----
__global__ void readout_kernel(const float* __restrict__ h,
                               const float* __restrict__ Wr1T,   // [128][64]
                               const float* __restrict__ b_r1,
                               const float* __restrict__ W_r2,
                               const float* __restrict__ b_r2,
                               const int* __restrict__ src,
                               const int* __restrict__ tgt,
                               float* __restrict__ out) {
    int lane = threadIdx.x;  // 64 threads, 1 wave; lane = hidden row index
    int sI = src[0];
    int tI = tgt[0];
    float acc = b_r1[lane];
#pragma unroll 8
    for (int k = 0; k < HID; ++k)
        acc += h[sI * HID + k] * Wr1T[k * 64 + lane];
#pragma unroll 8
    for (int k = 0; k < HID; ++k)
        acc += h[tI * HID + k] * Wr1T[(HID + k) * 64 + lane];
    float hid = fmaxf(acc, 0.0f);
    float p = hid * W_r2[lane];
#pragma unroll
    for (int off = 32; off > 0; off >>= 1)
        p += __shfl_down(p, off);
    if (lane == 0) out[0] = sigmoidf_(p + b_r2[0]);
}

extern "C" void kernel_launch(void* const* d_in, const int* in_sizes, int n_in,
                              void* d_out, int out_size, void* d_ws, size_t ws_size,
                              hipStream_t stream) {
    const float* A     = (const float*)d_in[0];
    const float* E     = (const float*)d_in[1];
    const float* X     = (const float*)d_in[2];
    const float* W_enc = (const float*)d_in[3];
    const float* b_enc = (const float*)d_in[4];
    const float* W_msg = (const float*)d_in[5];
    const float* b_msg = (const float*)d_in[6];
    const float* W_ih  = (const float*)d_in[7];
    const float* W_hh  = (const float*)d_in[8];
    const float* b_ih  = (const float*)d_in[9];
    const float* b_hh  = (const float*)d_in[10];
    const float* W_r1  = (const float*)d_in[11];
    const float* b_r1  = (const float*)d_in[12];
    const float* W_r2  = (const float*)d_in[13];
    const float* b_r2  = (const float*)d_in[14];
    const int*   src   = (const int*)d_in[15];
    const int*   tgt   = (const int*)d_in[16];
    // steps fixed at 3 in the reference.

    // workspace layout (floats)
    float* ws    = (float*)d_ws;
    float* h0    = ws;                     // N*HID
    float* h1    = h0 + N * HID;           // N*HID
    float* p0    = h1 + N * HID;           // N*HID
    float* p1    = p0 + N * HID;           // N*HID
    float* deg   = p1 + N * HID;           // N
    float* ev    = deg + N;                // N*MAXD
    int*   nbr   = (int*)(ev + N * MAXD);  // N*MAXD ints
    float* WihT  = (float*)(nbr + N * MAXD); // 64*192
    float* WhhT  = WihT + 64 * 192;          // 64*192
    float* WmsgT = WhhT + 64 * 192;          // 64*64
    float* Wr1T  = WmsgT + 64 * 64;          // 128*64

    init_kernel<<<1424, 256, 0, stream>>>(X, W_enc, b_enc, W_msg, b_msg,
                                          W_ih, W_hh, W_r1, A, E,
                                          h0, p0, nbr, ev, deg,
                                          WihT, WhhT, WmsgT, Wr1T);

    float* hc = h0; float* hn = h1;
    float* pc = p0; float* pn = p1;
    for (int s = 0; s < 3; ++s) {
        step_kernel<<<N / 4, 256, 0, stream>>>(pc, W_msg, b_msg, hc, nbr, ev, deg,
                                               WihT, WhhT, WmsgT, b_ih, b_hh,
                                               hn, pn, (s < 2) ? 1 : 0);
        float* t = hc; hc = hn; hn = t;
        t = pc; pc = pn; pn = t;
    }

    readout_kernel<<<1, 64, 0, stream>>>(hc, Wr1T, b_r1, W_r2, b_r2, src, tgt,
                                         (float*)d_out);
}